// Round 13
// baseline (212.305 us; speedup 1.0000x reference)
//
#include <hip/hip_runtime.h>
#include <hip/hip_bf16.h>
#include <stdint.h>

#define C_DIM 1024
#define MAXG 96     // max same-src group size; Binomial(8192,1/512) max ~40, 96 is ultra-safe
#define NSRC 512
#define NCHUNK 32   // E / 256

typedef __attribute__((ext_vector_type(8))) __bf16 bf16x8;
typedef __attribute__((ext_vector_type(8))) short short8;
typedef __attribute__((ext_vector_type(4))) float f32x4;

__device__ __forceinline__ short f2bf(float f) {
  unsigned u = __float_as_uint(f);
  unsigned r = (u + 0x7fffu + ((u >> 16) & 1u)) >> 16;  // RNE
  return (short)r;
}
__device__ __forceinline__ float bf2f(short s) {
  return __uint_as_float(((unsigned)(unsigned short)s) << 16);
}

// async global->LDS, 16B per lane. lds base must be wave-uniform (HW adds lane*16).
__device__ __forceinline__ void gload_lds16(const void* g, void* lds) {
  __builtin_amdgcn_global_load_lds(
      (const __attribute__((address_space(1))) unsigned int*)g,
      (__attribute__((address_space(3))) unsigned int*)lds,
      16, 0, 0);
}

// ---------------- converts (edge + node fused in one launch) ----------------
__global__ void cvt_bf16_2(const float* __restrict__ inA, int n4A,
                           const float* __restrict__ inB, int n4B,
                           short* __restrict__ outA, short* __restrict__ outB) {
  int i = blockIdx.x * blockDim.x + threadIdx.x;
  const float* in; short* out; int j;
  if (i < n4A) { in = inA; out = outA; j = i; }
  else if (i < n4A + n4B) { in = inB; out = outB; j = i - n4A; }
  else return;
  float4 v = ((const float4*)in)[j];
  short4 o;
  o.x = f2bf(v.x); o.y = f2bf(v.y); o.z = f2bf(v.z); o.w = f2bf(v.w);
  ((short4*)out)[j] = o;
}

// batched: out[z][n][k] = in[z][k][n] * scale[z]  (bf16), C_DIM x C_DIM each
__global__ void transpose_cvt3(const float* __restrict__ in0, const float* __restrict__ in1,
                               const float* __restrict__ in2, short* __restrict__ out0,
                               short* __restrict__ out1, short* __restrict__ out2,
                               float s0, float s1, float s2) {
  __shared__ float tile[32][33];
  const int z = blockIdx.z;
  const float* in = z == 0 ? in0 : (z == 1 ? in1 : in2);
  short* out = z == 0 ? out0 : (z == 1 ? out1 : out2);
  const float scale = z == 0 ? s0 : (z == 1 ? s1 : s2);
  int bx = blockIdx.x * 32, by = blockIdx.y * 32;
  int x = threadIdx.x, y4 = threadIdx.y * 4;
#pragma unroll
  for (int r = 0; r < 4; ++r)
    tile[y4 + r][x] = in[(size_t)(by + y4 + r) * C_DIM + bx + x];
  __syncthreads();
#pragma unroll
  for (int r = 0; r < 4; ++r)
    out[(size_t)(bx + y4 + r) * C_DIM + by + x] = f2bf(tile[x][y4 + r] * scale);
}

// ---------------- GEMM: C[M,N] = A[M,K](bf16) @ Bt[N,K](bf16)^T ----------------
// BK=64, 2-phase LDS double-buffer (prefetch issue before MFMA).
// EPI: 0 = f32 store, 1 = silu -> bf16 store, 2 = bf16 store + fused row-dot
//      (al_s[row] += Sum_cc C[row][cc]*as[cc], same for ad) via atomicAdd.
// 1D grid, XCD-swizzled (requires nwg % 8 == 0).
template <int EPI, int BM, int BN>
__global__ __launch_bounds__(256)
void gemm_bt(const short* __restrict__ A, const short* __restrict__ Bt,
             float* __restrict__ Cf, short* __restrict__ Cb,
             const float* __restrict__ as, const float* __restrict__ ad,
             float* __restrict__ als, float* __restrict__ ald,
             int M, int N, int K, int gm /* blocks along M */) {
  constexpr int WR = BM / 2, WC = BN / 2;
  constexpr int MT = WR / 16, NT = WC / 16;
  __shared__ __align__(16) short sA[2][BM * 64];
  __shared__ __align__(16) short sB[2][BN * 64];
  const int t = threadIdx.x;
  const int wave = t >> 6, lane = t & 63;
  const int wm = wave >> 1, wn = wave & 1;
  // bijective XCD swizzle: nwg % 8 == 0 guaranteed by caller
  const int nwg = gridDim.x, q = nwg >> 3;
  const int wg = (blockIdx.x & 7) * q + (blockIdx.x >> 3);
  const int bm = wg % gm, bn = wg / gm;
  const int rm = lane & 15, kg = lane >> 4;

  f32x4 acc[MT][NT];
#pragma unroll
  for (int i = 0; i < MT; ++i)
#pragma unroll
    for (int j = 0; j < NT; ++j) acc[i][j] = f32x4{0.f, 0.f, 0.f, 0.f};

  const size_t Abase = (size_t)bm * BM * K;
  const size_t Bbase = (size_t)bn * BN * K;
  const int nk = K >> 6;

  // stage(k-tile kt into buffer b): 256 lanes x 16B per pass; row=c>>3, k-part=(c&7)*8
#define STAGE(kt, b)                                                             \
  {                                                                              \
    const int k0_ = (kt) << 6;                                                   \
    _Pragma("unroll") for (int i = 0; i < BM / 32; ++i) {                        \
      int c = i * 256 + t;                                                       \
      gload_lds16(A + Abase + (size_t)(c >> 3) * K + k0_ + (c & 7) * 8,          \
                  &sA[b][(i * 256 + wave * 64) * 8]);                            \
    }                                                                            \
    _Pragma("unroll") for (int i = 0; i < BN / 32; ++i) {                        \
      int c = i * 256 + t;                                                       \
      gload_lds16(Bt + Bbase + (size_t)(c >> 3) * K + k0_ + (c & 7) * 8,         \
                  &sB[b][(i * 256 + wave * 64) * 8]);                            \
    }                                                                            \
  }

  STAGE(0, 0);
  __syncthreads();

  int cb = 0;
  for (int kk = 0; kk < nk; ++kk) {
    if (kk + 1 < nk) STAGE(kk + 1, cb ^ 1);  // prefetch issue: flies during MFMA below
#pragma unroll
    for (int kk2 = 0; kk2 < 2; ++kk2) {
      short8 af[MT], bfv[NT];
#pragma unroll
      for (int mt = 0; mt < MT; ++mt)
        af[mt] = *(const short8*)&sA[cb][(wm * WR + mt * 16 + rm) * 64 + kk2 * 32 + kg * 8];
#pragma unroll
      for (int nt = 0; nt < NT; ++nt)
        bfv[nt] = *(const short8*)&sB[cb][(wn * WC + nt * 16 + rm) * 64 + kk2 * 32 + kg * 8];
#pragma unroll
      for (int mt = 0; mt < MT; ++mt)
#pragma unroll
        for (int nt = 0; nt < NT; ++nt)
          acc[mt][nt] = __builtin_amdgcn_mfma_f32_16x16x32_bf16(
              __builtin_bit_cast(bf16x8, af[mt]),
              __builtin_bit_cast(bf16x8, bfv[nt]), acc[mt][nt], 0, 0, 0);
    }
    __syncthreads();  // drains prefetch vmcnt + this tile's reads; next iter flips
    cb ^= 1;
  }
#undef STAGE

  const int row0 = bm * BM + wm * WR;
  const int col0 = bn * BN + wn * WC;

  float as_v[NT], ad_v[NT];
  if (EPI == 2) {
#pragma unroll
    for (int nt = 0; nt < NT; ++nt) {
      as_v[nt] = as[col0 + nt * 16 + rm];
      ad_v[nt] = ad[col0 + nt * 16 + rm];
    }
  }

#pragma unroll
  for (int mt = 0; mt < MT; ++mt)
#pragma unroll
    for (int nt = 0; nt < NT; ++nt) {
      f32x4 v = acc[mt][nt];
      int r0 = row0 + mt * 16 + kg * 4;
      int cc = col0 + nt * 16 + rm;
#pragma unroll
      for (int j = 0; j < 4; ++j) {
        float x = v[j];
        if (EPI == 1) {
          float s = x / (1.f + __expf(-x));
          Cb[(size_t)(r0 + j) * N + cc] = f2bf(s);
        } else if (EPI == 2) {
          Cb[(size_t)(r0 + j) * N + cc] = f2bf(x);
        } else {
          Cf[(size_t)(r0 + j) * N + cc] = x;
        }
      }
    }

  if (EPI == 2) {
    // fused alpha row-dots: per (mt,j) row, partial over this lane's NT cols,
    // reduce across the 16 rm-lanes (xor bits 0-3 keep kg group), rm==0 atomically adds.
#pragma unroll
    for (int mt = 0; mt < MT; ++mt)
#pragma unroll
      for (int j = 0; j < 4; ++j) {
        float ps = 0.f, pd = 0.f;
#pragma unroll
        for (int nt = 0; nt < NT; ++nt) {
          float x = acc[mt][nt][j];
          ps += x * as_v[nt];
          pd += x * ad_v[nt];
        }
#pragma unroll
        for (int m = 1; m < 16; m <<= 1) {
          ps += __shfl_xor(ps, m);
          pd += __shfl_xor(pd, m);
        }
        if (rm == 0) {
          int row = row0 + mt * 16 + kg * 4 + j;
          atomicAdd(&als[row], ps);
          atomicAdd(&ald[row], pd);
        }
      }
  }
}

// ---------------- group structure: counting-sort style, no scans ----------------
// hist[s*NCHUNK + b] = #{e in chunk b : src[e]==s && valid}; every slot written.
// Also zero-inits ALs/ALd (poisoned 0xAA by harness; gemm's atomics accumulate).
__global__ __launch_bounds__(256)
void group_hist(const int* __restrict__ src, const int* __restrict__ dst,
                int* __restrict__ hist, float* __restrict__ als,
                float* __restrict__ ald) {
  __shared__ int h[NSRC];
  const int b = blockIdx.x, t = threadIdx.x;
  h[t] = 0; h[t + 256] = 0;
  int e = b * 256 + t;  // 32 blocks x 256 = E exactly
  als[e] = 0.f;
  ald[e] = 0.f;
  __syncthreads();
  int s = src[e];
  bool m = (s != dst[e]);
  if (m) atomicAdd(&h[s], 1);
  __syncthreads();
  hist[(size_t)t * NCHUNK + b] = h[t];
  hist[(size_t)(t + 256) * NCHUNK + b] = h[t + 256];
}

// epos[e] = rank of e among valid same-src edges (ascending e); glist[s*MAXG+p] = e.
__global__ __launch_bounds__(256)
void group_scatter(const int* __restrict__ src, const int* __restrict__ dst,
                   const int* __restrict__ hist, int* __restrict__ glist,
                   int* __restrict__ epos) {
  __shared__ int ssrc[256];
  __shared__ unsigned char sval[256];
  const int b = blockIdx.x, t = threadIdx.x;
  int e = b * 256 + t;
  int s = src[e];
  bool m = (s != dst[e]);
  ssrc[t] = s;
  sval[t] = m ? 1 : 0;
  __syncthreads();
  if (!m) return;
  int p = 0;
  for (int c = 0; c < b; ++c) p += hist[(size_t)s * NCHUNK + c];  // earlier chunks
  for (int j = 0; j < t; ++j) p += (ssrc[j] == s) & sval[j];      // stable intra-chunk rank
  if (p < MAXG) { glist[s * MAXG + p] = e; epos[e] = p; }
  else epos[e] = MAXG;  // statistically unreachable; degrade gracefully
}

// ---------------- attention output: one block per target edge, no scan ----------------
__global__ __launch_bounds__(256)
void attn_out(const int* __restrict__ src, const int* __restrict__ dst,
              const short* __restrict__ H, const float* __restrict__ als,
              const float* __restrict__ ald, const int* __restrict__ glist,
              const int* __restrict__ epos, const float* __restrict__ bias,
              float* __restrict__ out) {
  const int i = blockIdx.x;
  const int t = threadIdx.x;
  const int s = src[i];
  const int c0 = t * 4;
  if (s == dst[i]) {  // invalid edge: only the artificial self-loop attends
    short4 hv = *(const short4*)&H[(size_t)i * C_DIM + c0];
    float4 b4 = *(const float4*)&bias[c0];
    float4 o;
    o.x = bf2f(hv.x) + b4.x; o.y = bf2f(hv.y) + b4.y;
    o.z = bf2f(hv.z) + b4.z; o.w = bf2f(hv.w) + b4.w;
    *(float4*)&out[(size_t)i * C_DIM + c0] = o;
    return;
  }
  __shared__ int eid[MAXG + 1];
  __shared__ float ash[MAXG + 1];
  __shared__ float alv[MAXG + 1];
  const int p = epos[i];        // #earlier same-src valid edges
  if (t < p) {
    int e = glist[s * MAXG + t];
    eid[t] = e;
    ash[t] = als[e];
  }
  if (t == 0) { eid[p] = i; ash[p] = als[i]; }  // self-loop
  __syncthreads();
  const int L = p + 1;
  const float adi = ald[i];
  float mx = -1e30f;
  for (int q = 0; q < L; ++q) {
    float x = ash[q] + adi;
    x = x > 0.f ? x : 0.2f * x;
    mx = fmaxf(mx, x);
  }
  float ssum = 0.f;
  for (int q = 0; q < L; ++q) {
    float x = ash[q] + adi;
    x = x > 0.f ? x : 0.2f * x;
    ssum += __expf(x - mx);
  }
  float rs = 1.f / ssum;
  if (t < L) {
    float x = ash[t] + adi;
    x = x > 0.f ? x : 0.2f * x;
    alv[t] = __expf(x - mx) * rs;
  }
  __syncthreads();
  float4 acc = *(const float4*)&bias[c0];
  for (int q = 0; q < L; ++q) {
    float a = alv[q];
    short4 hv = *(const short4*)&H[(size_t)eid[q] * C_DIM + c0];
    acc.x += a * bf2f(hv.x); acc.y += a * bf2f(hv.y);
    acc.z += a * bf2f(hv.z); acc.w += a * bf2f(hv.w);
  }
  *(float4*)&out[(size_t)i * C_DIM + c0] = acc;
}

extern "C" void kernel_launch(void* const* d_in, const int* in_sizes, int n_in,
                              void* d_out, int out_size, void* d_ws, size_t ws_size,
                              hipStream_t stream) {
  const float* edge_f = (const float*)d_in[0];
  const float* node_f = (const float*)d_in[1];
  const int*   eidx   = (const int*)d_in[2];
  const float* gat_w  = (const float*)d_in[3];
  const float* att_s  = (const float*)d_in[4];
  const float* att_d  = (const float*)d_in[5];
  const float* gat_b  = (const float*)d_in[6];
  const float* w0     = (const float*)d_in[7];
  const float* w1     = (const float*)d_in[8];

  const int E = in_sizes[0] / C_DIM;  // 8192
  const int N = in_sizes[1] / C_DIM;  // 512
  const int* src = eidx;
  const int* dst = eidx + E;
  float* out_edge = (float*)d_out;
  float* out_node = out_edge + (size_t)E * C_DIM;

  char* ws = (char*)d_ws;
  short* Xb  = (short*)ws; ws += (size_t)E * C_DIM * 2;
  short* Wt  = (short*)ws; ws += (size_t)C_DIM * C_DIM * 2;
  short* W0t = (short*)ws; ws += (size_t)C_DIM * C_DIM * 2;
  short* W1t = (short*)ws; ws += (size_t)C_DIM * C_DIM * 2;
  short* Xnb = (short*)ws; ws += (size_t)N * C_DIM * 2;
  short* H1b = (short*)ws; ws += (size_t)N * C_DIM * 2;
  short* H   = (short*)ws; ws += (size_t)E * C_DIM * 2;  // h in bf16
  float* ALs = (float*)ws; ws += (size_t)E * 4;
  float* ALd = (float*)ws; ws += (size_t)E * 4;
  int*   Glist = (int*)ws; ws += (size_t)NSRC * MAXG * 4;
  int*   Epos  = (int*)ws; ws += (size_t)E * 4;
  int*   Hist  = (int*)ws; ws += (size_t)NSRC * NCHUNK * 4;

  // group structure (depends only on edge_index) + ALs/ALd zero-init
  group_hist<<<dim3(NCHUNK), 256, 0, stream>>>(src, dst, Hist, ALs, ALd);
  group_scatter<<<dim3(NCHUNK), 256, 0, stream>>>(src, dst, Hist, Glist, Epos);

  const int n4e = E * C_DIM / 4, n4n = N * C_DIM / 4;
  cvt_bf16_2<<<dim3((n4e + n4n + 255) / 256), 256, 0, stream>>>(
      edge_f, n4e, node_f, n4n, Xb, Xnb);
  transpose_cvt3<<<dim3(32, 32, 3), dim3(32, 8), 0, stream>>>(
      gat_w, w0, w1, Wt, W0t, W1t, 1.0f, 0.03125f, 1.6790524f * 0.03125f);

  // h = X @ W (bf16 out) + fused alpha dots; grid 1024 = 128x8, %8==0 -> swizzle ok
  gemm_bt<2, 64, 128><<<dim3((E / 64) * (C_DIM / 128)), 256, 0, stream>>>(
      Xb, Wt, nullptr, H, att_s, att_d, ALs, ALd, E, C_DIM, C_DIM, E / 64);
  attn_out<<<dim3(E), 256, 0, stream>>>(src, dst, H, ALs, ALd, Glist, Epos, gat_b, out_edge);

  // MLP: out_node = silu(Xn @ W0') @ W1'  (32x64 tiles, 256 blocks = 1/CU, %8==0)
  gemm_bt<1, 32, 64><<<dim3((N / 32) * (C_DIM / 64)), 256, 0, stream>>>(
      Xnb, W0t, nullptr, H1b, nullptr, nullptr, nullptr, nullptr, N, C_DIM, C_DIM, N / 32);
  gemm_bt<0, 32, 64><<<dim3((N / 32) * (C_DIM / 64)), 256, 0, stream>>>(
      H1b, W1t, out_node, nullptr, nullptr, nullptr, nullptr, nullptr, N, C_DIM, C_DIM, N / 32);
}